// Round 20
// baseline (268.351 us; speedup 1.0000x reference)
//
#include <hip/hip_runtime.h>
#include <math.h>

#define C_IN   64
#define T_DIM  256
#define V_DIM  25
#define C_OUT  256
#define S_DIM  3
#define BN_EPS 1e-5f

#define SC       (S_DIM * C_IN)          // 192
#define TW       (T_DIM * V_DIM)         // 6400
#define AP_PER_N (S_DIM * V_DIM * V_DIM) // 1875
#define LDB      200                     // sXa row stride in bf16 (400 B)
#define LDY      204                     // yS row stride in f32 (816 B, breaks bank alias)
#define NR       32                      // atomic replica count

#define NBINS    (NR * 2 * C_OUT)        // 16384
#define NAP      (64 * AP_PER_N)         // 120000 (n=64)
#define NAFB     (64 * 6 * 64 * 8)       // 196608
#define NWT      (C_OUT * SC)            // 49152
#define PREP_TOT (NBINS + NAP + NAFB + NWT)
#define NXU      (64 * 128 * 128 * 16)   // x_re uints (2 bf16 each)
#define PREP_ALL (PREP_TOT + NXU)

typedef __attribute__((ext_vector_type(8))) short bf16x8;
typedef __attribute__((ext_vector_type(4))) float f32x4;

__device__ __forceinline__ unsigned short f2bf(float f) {
    unsigned u = __builtin_bit_cast(unsigned, f);
    unsigned r = u + 0x7fffu + ((u >> 16) & 1u);
    return (unsigned short)(r >> 16);
}

// Native casts -> compiler emits HW cvt (proven R11).
__device__ __forceinline__ unsigned pk_bf16(float a, float b) {
    unsigned short ul = __builtin_bit_cast(unsigned short, (__bf16)a);
    unsigned short uh = __builtin_bit_cast(unsigned short, (__bf16)b);
    return (unsigned)ul | ((unsigned)uh << 16);
}

// Non-temporal float2 store: y is write-once -> bypass L2.
__device__ __forceinline__ void nt_store_f2(float2 v, float* p) {
    __builtin_nontemporal_store(__builtin_bit_cast(double, v), (double*)p);
}

// ---------------------------------------------------------------------------
// Merged prep: zero bins | out_ap=tanh | afb pack | wt_b pack | x relayout.
// ---------------------------------------------------------------------------
__global__ void k_prep(const float* __restrict__ A, const float* __restrict__ A_pers,
                       const float* __restrict__ conv_w, const float* __restrict__ x,
                       float* __restrict__ bins, float* __restrict__ out_ap,
                       unsigned short* __restrict__ afb, unsigned short* __restrict__ wt_b,
                       unsigned* __restrict__ x_re) {
    int i = blockIdx.x * 256 + threadIdx.x;
    if (i < NBINS) {
        bins[i] = 0.f;
        return;
    }
    i -= NBINS;
    if (i < NAP) {
        out_ap[i] = tanhf(A_pers[i]);
        return;
    }
    i -= NAP;
    if (i < NAFB) {
        int j    = i;
        int k    = j & 7;
        int lane = (j >> 3) & 63;
        int nt   = (j >> 9) & 1;
        int sn   = j >> 10;
        int s    = sn % 3;
        int n    = sn / 3;
        int v    = ((lane >> 4) << 3) + k;
        int w    = nt * 16 + (lane & 15);
        float val = 0.f;
        if (v < V_DIM && w < V_DIM)
            val = A[(s * V_DIM + v) * V_DIM + w] +
                  tanhf(A_pers[((n * S_DIM + s) * V_DIM + v) * V_DIM + w]);
        afb[j] = f2bf(val);
        return;
    }
    i -= NAFB;
    if (i < NWT) {
        int o  = i / SC;
        int sc = i - o * SC;
        int s  = sc >> 6, c = sc & 63;
        wt_b[i] = f2bf(conv_w[(s * C_OUT + o) * C_IN + c]);
        return;
    }
    i -= NWT;
    if (i < NXU) {
        int tile = i >> 11;          // 2048 uints per tile
        int rem  = i & 2047;
        int row  = rem >> 4;         // 0..127 = 2c+t
        int vp   = rem & 15;         // uint col (v pair)
        int n = tile >> 7, tp = tile & 127;
        int c = row >> 1, t = row & 1;
        const float* src = x + (size_t)n * (C_IN * TW) + (size_t)c * TW + (2 * tp + t) * V_DIM;
        int v0 = vp * 2;
        unsigned lo = (v0 < V_DIM)     ? f2bf(src[v0])     : 0;
        unsigned hi = (v0 + 1 < V_DIM) ? f2bf(src[v0 + 1]) : 0;
        x_re[i] = lo | (hi << 16);
    }
}

// ---------------------------------------------------------------------------
// k_gsum8: pass0, 8 t-pairs per block (4 half-iterations over a 2-tile sXa).
// Loop-carried state is only s1a/s2a[4] (8 floats) -- acc[2][4] is folded
// per-half, avoiding the R15/R16 register cliff. Prologue amortized 2x vs tp4.
// Flat grid 4096 with XCD-pinning (4 z-siblings share an XCD's L2 for x_re).
// ---------------------------------------------------------------------------
__global__ __launch_bounds__(256, 3) void k_gsum8(const unsigned short* __restrict__ x_re,
                                                  const unsigned short* __restrict__ afb,
                                                  const unsigned short* __restrict__ wt_b,
                                                  float* __restrict__ bins) {
    __shared__ __align__(16) unsigned short sXa[2][64 * LDB];  // 51.2 KB

    // XCD-pinned decode: group's 4 z-blocks all ≡ xcd (mod 8)
    const int d    = blockIdx.x;            // 0..4095
    const int xcd  = d & 7;
    const int q8   = d >> 3;
    const int z    = q8 & 3;                // o-quarter (64 channels)
    const int g    = (q8 >> 2) * 8 + xcd;   // group 0..1023 = n*16 + tp8
    const int tp8  = g & 15;
    const int nIdx = g >> 4;

    const int tid  = threadIdx.x;
    const int lane = tid & 63;
    const int wv   = tid >> 6;
    const int l15  = lane & 15;
    const int kg   = lane >> 4;
    const int obase = z * 64 + wv * 16;

    bf16x8 aF[6];
    {
        const unsigned short* wrow = wt_b + (size_t)(z * 64 + wv * 16 + l15) * SC + kg * 8;
#pragma unroll
        for (int ks = 0; ks < 6; ++ks)
            aF[ks] = *(const bf16x8*)(wrow + ks * 32);
    }
    bf16x8 bS[6];
    {
        const unsigned short* afbN = afb + (size_t)nIdx * (6 * 64 * 8);
#pragma unroll
        for (int sq = 0; sq < 6; ++sq)
            bS[sq] = *(const bf16x8*)(afbN + (sq * 64 + lane) * 8);
    }

    float s1a[4], s2a[4];
#pragma unroll
    for (int r = 0; r < 4; ++r) { s1a[r] = 0.f; s2a[r] = 0.f; }

#pragma unroll
    for (int h = 0; h < 4; ++h) {
        // stage-1 A-frags for this half's 2 tiles
        bf16x8 aX[2][2];
        {
            const unsigned short* xt0 = x_re + (size_t)(nIdx * 128 + tp8 * 8 + h * 2) * 4096;
#pragma unroll
            for (int u = 0; u < 2; ++u)
#pragma unroll
                for (int m2 = 0; m2 < 2; ++m2)
                    aX[u][m2] = *(const bf16x8*)(xt0 + u * 4096 + ((wv * 2 + m2) * 16 + l15) * 32 + kg * 8);
        }

        // stage 1: 24 MFMA/wave; packed bf16 b32 LDS writes
#pragma unroll
        for (int sq = 0; sq < 6; ++sq) {
            int s = sq >> 1, nt = sq & 1;
            int w = nt * 16 + l15;
#pragma unroll
            for (int u = 0; u < 2; ++u) {
#pragma unroll
                for (int m2 = 0; m2 < 2; ++m2) {
                    int mt = wv * 2 + m2;
                    f32x4 c4 = __builtin_amdgcn_mfma_f32_16x16x32_bf16(
                        aX[u][m2], bS[sq], (f32x4){0.f, 0.f, 0.f, 0.f}, 0, 0, 0);
                    if (w < V_DIM) {
                        unsigned u0 = pk_bf16(c4[0], c4[2]);   // t=0
                        unsigned u1 = pk_bf16(c4[1], c4[3]);   // t=1
                        unsigned col = s * 32 + mt * 4 + kg;
                        unsigned* dst = (unsigned*)sXa[u];
                        dst[w * (LDB / 2) + col]           = u0;
                        dst[(V_DIM + w) * (LDB / 2) + col] = u1;
                    }
                }
            }
        }
        __syncthreads();   // sXa ready for stage 2

        // stage 2: fresh acc per half, folded immediately into s1a/s2a
        f32x4 acc[2][4];
#pragma unroll
        for (int u = 0; u < 2; ++u)
#pragma unroll
            for (int nn = 0; nn < 4; ++nn) acc[u][nn] = (f32x4){0.f, 0.f, 0.f, 0.f};
#pragma unroll
        for (int ks = 0; ks < 6; ++ks) {
            bf16x8 bF[2][4];
#pragma unroll
            for (int u = 0; u < 2; ++u)
#pragma unroll
                for (int nn = 0; nn < 4; ++nn)
                    bF[u][nn] = *(const bf16x8*)(sXa[u] + (nn * 16 + l15) * LDB + ks * 32 + kg * 8);
            __builtin_amdgcn_s_setprio(1);
#pragma unroll
            for (int u = 0; u < 2; ++u)
#pragma unroll
                for (int nn = 0; nn < 4; ++nn)
                    acc[u][nn] = __builtin_amdgcn_mfma_f32_16x16x32_bf16(
                        aF[ks], bF[u][nn], acc[u][nn], 0, 0, 0);
            __builtin_amdgcn_s_setprio(0);
        }
#pragma unroll
        for (int r = 0; r < 4; ++r) {
#pragma unroll
            for (int u = 0; u < 2; ++u) {
                float v0 = acc[u][0][r], v1 = acc[u][1][r], v2 = acc[u][2][r];
                s1a[r] += v0 + v1 + v2;
                s2a[r] += v0 * v0 + v1 * v1 + v2 * v2;
                if (l15 < 2) {                   // tw = 48+l15 < 50
                    float v3 = acc[u][3][r];
                    s1a[r] += v3;
                    s2a[r] += v3 * v3;
                }
            }
        }
        if (h < 3) __syncthreads();   // next half's stage-1 overwrites sXa
    }

    // epilogue: shfl-reduce over l15, replica atomics
    const int rep = d & (NR - 1);
    float* b0 = bins + rep * 2 * C_OUT;
#pragma unroll
    for (int r = 0; r < 4; ++r) {
        float a = s1a[r], b = s2a[r];
#pragma unroll
        for (int off = 1; off < 16; off <<= 1) {
            a += __shfl_xor(a, off, 64);
            b += __shfl_xor(b, off, 64);
        }
        if (l15 == 0) {
            int o = obase + kg * 4 + r;
            atomicAdd(&b0[o], a);
            atomicAdd(&b0[C_OUT + o], b);
        }
    }
}

// ---------------------------------------------------------------------------
// k_gy: pass1 (unchanged from R19 best): flat grid 8192, XCD-pinned; tp4;
// acc[4][4] held; BN+ReLU via yS[64][204]; 800B-run nt y writes.
// ---------------------------------------------------------------------------
__global__ __launch_bounds__(256, 3) void k_gy(const unsigned short* __restrict__ x_re,
                                               const unsigned short* __restrict__ afb,
                                               const unsigned short* __restrict__ wt_b,
                                               float* __restrict__ y,
                                               const float2* __restrict__ ssv) {
    __shared__ __align__(16) char smem[64 * LDY * 4];    // 52224 B
    unsigned short* sXa = (unsigned short*)smem;         // [2][64*LDB] bf16 (51.2 KB)

    const int d    = blockIdx.x;            // 0..8191
    const int xcd  = d & 7;
    const int q8   = d >> 3;
    const int z    = q8 & 3;
    const int g    = (q8 >> 2) * 8 + xcd;   // group 0..2047 = n*32 + tp4
    const int tp4  = g & 31;
    const int nIdx = g >> 5;

    const int tid  = threadIdx.x;
    const int lane = tid & 63;
    const int wv   = tid >> 6;
    const int l15  = lane & 15;
    const int kg   = lane >> 4;
    const int obase = z * 64 + wv * 16;

    bf16x8 aF[6];
    {
        const unsigned short* wrow = wt_b + (size_t)(z * 64 + wv * 16 + l15) * SC + kg * 8;
#pragma unroll
        for (int ks = 0; ks < 6; ++ks)
            aF[ks] = *(const bf16x8*)(wrow + ks * 32);
    }
    bf16x8 bS[6];
    {
        const unsigned short* afbN = afb + (size_t)nIdx * (6 * 64 * 8);
#pragma unroll
        for (int sq = 0; sq < 6; ++sq)
            bS[sq] = *(const bf16x8*)(afbN + (sq * 64 + lane) * 8);
    }
    float2 sh[4];
#pragma unroll
    for (int r = 0; r < 4; ++r)
        sh[r] = ssv[obase + kg * 4 + r];

    f32x4 acc[4][4];
#pragma unroll
    for (int q = 0; q < 4; ++q)
#pragma unroll
        for (int nn = 0; nn < 4; ++nn) acc[q][nn] = (f32x4){0.f, 0.f, 0.f, 0.f};

#pragma unroll
    for (int h = 0; h < 2; ++h) {
        bf16x8 aX[2][2];
        {
            const unsigned short* xt0 = x_re + (size_t)(nIdx * 128 + tp4 * 4 + h * 2) * 4096;
#pragma unroll
            for (int u = 0; u < 2; ++u)
#pragma unroll
                for (int m2 = 0; m2 < 2; ++m2)
                    aX[u][m2] = *(const bf16x8*)(xt0 + u * 4096 + ((wv * 2 + m2) * 16 + l15) * 32 + kg * 8);
        }
#pragma unroll
        for (int sq = 0; sq < 6; ++sq) {
            int s = sq >> 1, nt = sq & 1;
            int w = nt * 16 + l15;
#pragma unroll
            for (int u = 0; u < 2; ++u) {
#pragma unroll
                for (int m2 = 0; m2 < 2; ++m2) {
                    int mt = wv * 2 + m2;
                    f32x4 c4 = __builtin_amdgcn_mfma_f32_16x16x32_bf16(
                        aX[u][m2], bS[sq], (f32x4){0.f, 0.f, 0.f, 0.f}, 0, 0, 0);
                    if (w < V_DIM) {
                        unsigned u0 = pk_bf16(c4[0], c4[2]);
                        unsigned u1 = pk_bf16(c4[1], c4[3]);
                        unsigned col = s * 32 + mt * 4 + kg;
                        unsigned* dst = (unsigned*)(sXa + u * 12800);
                        dst[w * (LDB / 2) + col]           = u0;
                        dst[(V_DIM + w) * (LDB / 2) + col] = u1;
                    }
                }
            }
        }
        __syncthreads();

#pragma unroll
        for (int ks = 0; ks < 6; ++ks) {
            bf16x8 bF[2][4];
#pragma unroll
            for (int u = 0; u < 2; ++u)
#pragma unroll
                for (int nn = 0; nn < 4; ++nn)
                    bF[u][nn] = *(const bf16x8*)(sXa + u * 12800 + (nn * 16 + l15) * LDB + ks * 32 + kg * 8);
            __builtin_amdgcn_s_setprio(1);
#pragma unroll
            for (int u = 0; u < 2; ++u)
#pragma unroll
                for (int nn = 0; nn < 4; ++nn)
                    acc[h * 2 + u][nn] = __builtin_amdgcn_mfma_f32_16x16x32_bf16(
                        aF[ks], bF[u][nn], acc[h * 2 + u][nn], 0, 0, 0);
            __builtin_amdgcn_s_setprio(0);
        }
        if (h == 0) __syncthreads();
    }

    __syncthreads();
    float* yS = (float*)smem;
#pragma unroll
    for (int r = 0; r < 4; ++r) {
        int ol = wv * 16 + kg * 4 + r;
        float sc = sh[r].x, sf = sh[r].y;
#pragma unroll
        for (int q = 0; q < 4; ++q) {
            float* sp = yS + ol * LDY + q * 50 + l15;
            sp[0]  = fmaxf(fmaf(acc[q][0][r], sc, sf), 0.f);
            sp[16] = fmaxf(fmaf(acc[q][1][r], sc, sf), 0.f);
            sp[32] = fmaxf(fmaf(acc[q][2][r], sc, sf), 0.f);
            if (l15 < 2)
                sp[48] = fmaxf(fmaf(acc[q][3][r], sc, sf), 0.f);
        }
    }
    __syncthreads();

    float* ydst = y + ((size_t)nIdx * C_OUT + z * 64) * TW + (size_t)tp4 * 200;
    int o = tid / 100, j2 = tid - o * 100;
#pragma unroll
    for (int k = 0; k < 25; ++k) {
        float2 v = *(const float2*)(yS + o * LDY + 2 * j2);
        nt_store_f2(v, ydst + (size_t)o * TW + 2 * j2);
        o += 2; j2 += 56;
        if (j2 >= 100) { j2 -= 100; ++o; }
    }
}

// ---------------------------------------------------------------------------
__global__ void k_stats(const float* __restrict__ bins, const float* __restrict__ bn_w,
                        const float* __restrict__ bn_b, float2* __restrict__ ssv, int n) {
    int o = threadIdx.x;
    float s1 = 0.f, s2 = 0.f;
    for (int rp = 0; rp < NR; ++rp) {
        s1 += bins[rp * 2 * C_OUT + o];
        s2 += bins[rp * 2 * C_OUT + C_OUT + o];
    }
    float cnt   = (float)n * (float)TW;
    float mean  = s1 / cnt;
    float var   = s2 / cnt - mean * mean;
    float scale = bn_w[o] * rsqrtf(var + BN_EPS);
    ssv[o] = make_float2(scale, bn_b[o] - mean * scale);
}

// ---------------------------------------------------------------------------
extern "C" void kernel_launch(void* const* d_in, const int* in_sizes, int n_in,
                              void* d_out, int out_size, void* d_ws, size_t ws_size,
                              hipStream_t stream) {
    const float* x      = (const float*)d_in[0];
    const float* A      = (const float*)d_in[1];
    const float* A_pers = (const float*)d_in[2];
    const float* conv_w = (const float*)d_in[3];
    // d_in[4] = conv_b: cancels under training-mode BatchNorm -> unused
    const float* bn_w   = (const float*)d_in[5];
    const float* bn_b   = (const float*)d_in[6];

    const int n = in_sizes[0] / (C_IN * TW);   // 64

    float* out_ap = (float*)d_out;
    float* y      = (float*)d_out + (size_t)n * AP_PER_N;

    // ws layout (~67.7 MB total)
    float*  bins = (float*)d_ws;                                    // 64 KB
    float2* ssv  = (float2*)(bins + NBINS);                         // 2 KB
    unsigned short* afb  = (unsigned short*)((char*)(ssv + C_OUT)); // 384 KB
    unsigned short* wt_b = afb + (size_t)NAFB;                      // 96 KB
    unsigned short* x_re = wt_b + (size_t)NWT;                      // 67.1 MB

    // single merged prep launch: bins zero + out_ap + afb + wt_b + x relayout
    k_prep<<<(PREP_ALL + 255) / 256, 256, 0, stream>>>(A, A_pers, conv_w, x,
                                                       bins, out_ap, afb, wt_b,
                                                       (unsigned*)x_re);

    k_gsum8<<<dim3(T_DIM / 16 * 64 * 4), 256, 0, stream>>>(x_re, afb, wt_b, bins);
    k_stats<<<1, 256, 0, stream>>>(bins, bn_w, bn_b, ssv, n);
    k_gy<<<dim3(T_DIM / 8 * 64 * 4), 256, 0, stream>>>(x_re, afb, wt_b, y, ssv);
}

// Round 21
// 258.463 us; speedup vs baseline: 1.0383x; 1.0383x over previous
//
#include <hip/hip_runtime.h>
#include <math.h>

#define C_IN   64
#define T_DIM  256
#define V_DIM  25
#define C_OUT  256
#define S_DIM  3
#define BN_EPS 1e-5f

#define SC       (S_DIM * C_IN)          // 192
#define TW       (T_DIM * V_DIM)         // 6400
#define AP_PER_N (S_DIM * V_DIM * V_DIM) // 1875
#define LDB      200                     // sXa row stride in bf16 (400 B)
#define LDY      204                     // yS row stride in f32 (816 B, breaks bank alias)
#define NR       32                      // atomic replica count

#define NBINS    (NR * 2 * C_OUT)        // 16384
#define NAP      (64 * AP_PER_N)         // 120000 (n=64)
#define NAFB     (64 * 6 * 64 * 8)       // 196608
#define NWT      (C_OUT * SC)            // 49152
#define PREP_TOT (NBINS + NAP + NAFB + NWT)
#define NXU      (64 * 128 * 128 * 16)   // x_re uints (2 bf16 each)
#define PREP_ALL (PREP_TOT + NXU)

typedef __attribute__((ext_vector_type(8))) short bf16x8;
typedef __attribute__((ext_vector_type(4))) float f32x4;

__device__ __forceinline__ unsigned short f2bf(float f) {
    unsigned u = __builtin_bit_cast(unsigned, f);
    unsigned r = u + 0x7fffu + ((u >> 16) & 1u);
    return (unsigned short)(r >> 16);
}

// Native casts -> compiler emits HW cvt (proven R11).
__device__ __forceinline__ unsigned pk_bf16(float a, float b) {
    unsigned short ul = __builtin_bit_cast(unsigned short, (__bf16)a);
    unsigned short uh = __builtin_bit_cast(unsigned short, (__bf16)b);
    return (unsigned)ul | ((unsigned)uh << 16);
}

// Non-temporal float2 store: y is write-once -> bypass L2.
__device__ __forceinline__ void nt_store_f2(float2 v, float* p) {
    __builtin_nontemporal_store(__builtin_bit_cast(double, v), (double*)p);
}

// ---------------------------------------------------------------------------
// Merged prep: zero bins | out_ap=tanh | afb pack | wt_b pack | x relayout.
// ---------------------------------------------------------------------------
__global__ void k_prep(const float* __restrict__ A, const float* __restrict__ A_pers,
                       const float* __restrict__ conv_w, const float* __restrict__ x,
                       float* __restrict__ bins, float* __restrict__ out_ap,
                       unsigned short* __restrict__ afb, unsigned short* __restrict__ wt_b,
                       unsigned* __restrict__ x_re) {
    int i = blockIdx.x * 256 + threadIdx.x;
    if (i < NBINS) {
        bins[i] = 0.f;
        return;
    }
    i -= NBINS;
    if (i < NAP) {
        out_ap[i] = tanhf(A_pers[i]);
        return;
    }
    i -= NAP;
    if (i < NAFB) {
        int j    = i;
        int k    = j & 7;
        int lane = (j >> 3) & 63;
        int nt   = (j >> 9) & 1;
        int sn   = j >> 10;
        int s    = sn % 3;
        int n    = sn / 3;
        int v    = ((lane >> 4) << 3) + k;
        int w    = nt * 16 + (lane & 15);
        float val = 0.f;
        if (v < V_DIM && w < V_DIM)
            val = A[(s * V_DIM + v) * V_DIM + w] +
                  tanhf(A_pers[((n * S_DIM + s) * V_DIM + v) * V_DIM + w]);
        afb[j] = f2bf(val);
        return;
    }
    i -= NAFB;
    if (i < NWT) {
        int o  = i / SC;
        int sc = i - o * SC;
        int s  = sc >> 6, c = sc & 63;
        wt_b[i] = f2bf(conv_w[(s * C_OUT + o) * C_IN + c]);
        return;
    }
    i -= NWT;
    if (i < NXU) {
        int tile = i >> 11;          // 2048 uints per tile
        int rem  = i & 2047;
        int row  = rem >> 4;         // 0..127 = 2c+t
        int vp   = rem & 15;         // uint col (v pair)
        int n = tile >> 7, tp = tile & 127;
        int c = row >> 1, t = row & 1;
        const float* src = x + (size_t)n * (C_IN * TW) + (size_t)c * TW + (2 * tp + t) * V_DIM;
        int v0 = vp * 2;
        unsigned lo = (v0 < V_DIM)     ? f2bf(src[v0])     : 0;
        unsigned hi = (v0 + 1 < V_DIM) ? f2bf(src[v0 + 1]) : 0;
        x_re[i] = lo | (hi << 16);
    }
}

// ---------------------------------------------------------------------------
// k_gemm<PASS>: flat grid 8192 with XCD-pinning swizzle: the 4 z-quarters of
// each (tp4, n) group share one XCD (d = xcd + 8*(4*grp + z)) -> their common
// x_re/afb reads hit that XCD's L2 instead of 4x HBM fetch.
// Per block: two half-iterations over a 2-tile sXa; acc[4][4] held.
// PASS 0: channel sum/sumsq -> shfl-reduce + replica atomics.
// PASS 1: BN+ReLU, f32 transpose into yS[64][204] -> 800B-run nt y writes.
// NOTE (R15/R16 lesson): z-loop-in-block spills registers; keep z in grid.
// NOTE (R20 lesson): widening pass0 to 8 t-pairs/block regressed (more serial
// barrier rounds per block); tp4 is the sweet spot.
// NOTE (R19): sXa pad rows tw=50..63 left UNINITIALIZED — their MFMA output
// columns (tw>=50) are discarded by every consumer (l15<2 guards).
// ---------------------------------------------------------------------------
template <int PASS>
__global__ __launch_bounds__(256, 3) void k_gemm(const unsigned short* __restrict__ x_re,
                                                 const unsigned short* __restrict__ afb,
                                                 const unsigned short* __restrict__ wt_b,
                                                 float* __restrict__ y,
                                                 float* __restrict__ bins,
                                                 const float2* __restrict__ ssv) {
    __shared__ __align__(16) char smem[64 * LDY * 4];    // 52224 B
    unsigned short* sXa = (unsigned short*)smem;         // [2][64*LDB] bf16 (51.2 KB)

    // XCD-pinned decode: group's 4 z-blocks all ≡ xcd (mod 8)
    const int d    = blockIdx.x;            // 0..8191
    const int xcd  = d & 7;
    const int q8   = d >> 3;
    const int z    = q8 & 3;                // o-quarter (64 channels)
    const int g    = (q8 >> 2) * 8 + xcd;   // group 0..2047 = n*32 + tp4
    const int tp4  = g & 31;
    const int nIdx = g >> 5;

    const int tid  = threadIdx.x;
    const int lane = tid & 63;
    const int wv   = tid >> 6;
    const int l15  = lane & 15;
    const int kg   = lane >> 4;
    const int obase = z * 64 + wv * 16;

    // ---- register-resident stage-2 weights (wave's 16-o strip): 6 x b128 ----
    bf16x8 aF[6];
    {
        const unsigned short* wrow = wt_b + (size_t)(z * 64 + wv * 16 + l15) * SC + kg * 8;
#pragma unroll
        for (int ks = 0; ks < 6; ++ks)
            aF[ks] = *(const bf16x8*)(wrow + ks * 32);
    }
    // ---- stage-1 B-frags (Af) ----
    bf16x8 bS[6];
    {
        const unsigned short* afbN = afb + (size_t)nIdx * (6 * 64 * 8);
#pragma unroll
        for (int sq = 0; sq < 6; ++sq)
            bS[sq] = *(const bf16x8*)(afbN + (sq * 64 + lane) * 8);
    }
    // ---- pass1: hoist BN scale/shift loads off the epilogue critical path ----
    float2 sh[4];
    if (PASS == 1) {
#pragma unroll
        for (int r = 0; r < 4; ++r)
            sh[r] = ssv[obase + kg * 4 + r];
    }

    f32x4 acc[4][4];
#pragma unroll
    for (int q = 0; q < 4; ++q)
#pragma unroll
        for (int nn = 0; nn < 4; ++nn) acc[q][nn] = (f32x4){0.f, 0.f, 0.f, 0.f};

#pragma unroll
    for (int h = 0; h < 2; ++h) {
        // ---- stage-1 A-frags for this half's 2 tiles ----
        bf16x8 aX[2][2];
        {
            const unsigned short* xt0 = x_re + (size_t)(nIdx * 128 + tp4 * 4 + h * 2) * 4096;
#pragma unroll
            for (int u = 0; u < 2; ++u)
#pragma unroll
                for (int m2 = 0; m2 < 2; ++m2)
                    aX[u][m2] = *(const bf16x8*)(xt0 + u * 4096 + ((wv * 2 + m2) * 16 + l15) * 32 + kg * 8);
        }

        // ---- stage 1: 24 MFMA/wave; packed bf16 b32 LDS writes ----
#pragma unroll
        for (int sq = 0; sq < 6; ++sq) {
            int s = sq >> 1, nt = sq & 1;
            int w = nt * 16 + l15;
#pragma unroll
            for (int u = 0; u < 2; ++u) {
#pragma unroll
                for (int m2 = 0; m2 < 2; ++m2) {
                    int mt = wv * 2 + m2;
                    f32x4 c4 = __builtin_amdgcn_mfma_f32_16x16x32_bf16(
                        aX[u][m2], bS[sq], (f32x4){0.f, 0.f, 0.f, 0.f}, 0, 0, 0);
                    if (w < V_DIM) {
                        unsigned u0 = pk_bf16(c4[0], c4[2]);   // t=0
                        unsigned u1 = pk_bf16(c4[1], c4[3]);   // t=1
                        unsigned col = s * 32 + mt * 4 + kg;
                        unsigned* dst = (unsigned*)(sXa + u * 12800);
                        dst[w * (LDB / 2) + col]           = u0;
                        dst[(V_DIM + w) * (LDB / 2) + col] = u1;
                    }
                }
            }
        }
        __syncthreads();   // sXa ready for stage 2

        // ---- stage 2: M=16/wave, K=192; acc[h*2+u]; MFMA cluster at prio 1 ----
#pragma unroll
        for (int ks = 0; ks < 6; ++ks) {
            bf16x8 bF[2][4];
#pragma unroll
            for (int u = 0; u < 2; ++u)
#pragma unroll
                for (int nn = 0; nn < 4; ++nn)
                    bF[u][nn] = *(const bf16x8*)(sXa + u * 12800 + (nn * 16 + l15) * LDB + ks * 32 + kg * 8);
            __builtin_amdgcn_s_setprio(1);
#pragma unroll
            for (int u = 0; u < 2; ++u)
#pragma unroll
                for (int nn = 0; nn < 4; ++nn)
                    acc[h * 2 + u][nn] = __builtin_amdgcn_mfma_f32_16x16x32_bf16(
                        aF[ks], bF[u][nn], acc[h * 2 + u][nn], 0, 0, 0);
            __builtin_amdgcn_s_setprio(0);
        }
        if (h == 0) __syncthreads();   // half-2 stage-1 may overwrite sXa
    }

    if (PASS == 0) {
        // ---- channel sums over all 4 tiles -> shfl-reduce, replica atomics ----
        const int rep = d & (NR - 1);
        float* b0 = bins + rep * 2 * C_OUT;
#pragma unroll
        for (int r = 0; r < 4; ++r) {
            float s1 = 0.f, s2 = 0.f;
#pragma unroll
            for (int q = 0; q < 4; ++q) {
                float v0 = acc[q][0][r], v1 = acc[q][1][r], v2 = acc[q][2][r];
                s1 += v0 + v1 + v2;
                s2 += v0 * v0 + v1 * v1 + v2 * v2;
                if (l15 < 2) {                   // tw = 48+l15 < 50
                    float v3 = acc[q][3][r];
                    s1 += v3;
                    s2 += v3 * v3;
                }
            }
#pragma unroll
            for (int off = 1; off < 16; off <<= 1) {
                s1 += __shfl_xor(s1, off, 64);
                s2 += __shfl_xor(s2, off, 64);
            }
            if (l15 == 0) {
                int o = obase + kg * 4 + r;
                atomicAdd(&b0[o], s1);
                atomicAdd(&b0[C_OUT + o], s2);
            }
        }
    } else {
        // ---- BN+ReLU; transpose via yS [64][204] f32; 800B-run nt y writes ----
        __syncthreads();                 // all sXa reads done before overwrite
        float* yS = (float*)smem;
#pragma unroll
        for (int r = 0; r < 4; ++r) {
            int ol = wv * 16 + kg * 4 + r;
            float sc = sh[r].x, sf = sh[r].y;
#pragma unroll
            for (int q = 0; q < 4; ++q) {
                float* sp = yS + ol * LDY + q * 50 + l15;
                sp[0]  = fmaxf(fmaf(acc[q][0][r], sc, sf), 0.f);
                sp[16] = fmaxf(fmaf(acc[q][1][r], sc, sf), 0.f);
                sp[32] = fmaxf(fmaf(acc[q][2][r], sc, sf), 0.f);
                if (l15 < 2)
                    sp[48] = fmaxf(fmaf(acc[q][3][r], sc, sf), 0.f);
            }
        }
        __syncthreads();

        // dump: 6400 float2; rows of 200 f32 = 800B contiguous per o;
        // incremental (o, j2) stepping (no per-iter division)
        float* ydst = y + ((size_t)nIdx * C_OUT + z * 64) * TW + (size_t)tp4 * 200;
        int o = tid / 100, j2 = tid - o * 100;
#pragma unroll
        for (int k = 0; k < 25; ++k) {
            float2 v = *(const float2*)(yS + o * LDY + 2 * j2);
            nt_store_f2(v, ydst + (size_t)o * TW + 2 * j2);
            o += 2; j2 += 56;
            if (j2 >= 100) { j2 -= 100; ++o; }
        }
    }
}

// ---------------------------------------------------------------------------
__global__ void k_stats(const float* __restrict__ bins, const float* __restrict__ bn_w,
                        const float* __restrict__ bn_b, float2* __restrict__ ssv, int n) {
    int o = threadIdx.x;
    float s1 = 0.f, s2 = 0.f;
    for (int rp = 0; rp < NR; ++rp) {
        s1 += bins[rp * 2 * C_OUT + o];
        s2 += bins[rp * 2 * C_OUT + C_OUT + o];
    }
    float cnt   = (float)n * (float)TW;
    float mean  = s1 / cnt;
    float var   = s2 / cnt - mean * mean;
    float scale = bn_w[o] * rsqrtf(var + BN_EPS);
    ssv[o] = make_float2(scale, bn_b[o] - mean * scale);
}

// ---------------------------------------------------------------------------
extern "C" void kernel_launch(void* const* d_in, const int* in_sizes, int n_in,
                              void* d_out, int out_size, void* d_ws, size_t ws_size,
                              hipStream_t stream) {
    const float* x      = (const float*)d_in[0];
    const float* A      = (const float*)d_in[1];
    const float* A_pers = (const float*)d_in[2];
    const float* conv_w = (const float*)d_in[3];
    // d_in[4] = conv_b: cancels under training-mode BatchNorm -> unused
    const float* bn_w   = (const float*)d_in[5];
    const float* bn_b   = (const float*)d_in[6];

    const int n = in_sizes[0] / (C_IN * TW);   // 64

    float* out_ap = (float*)d_out;
    float* y      = (float*)d_out + (size_t)n * AP_PER_N;

    // ws layout (~67.7 MB total)
    float*  bins = (float*)d_ws;                                    // 64 KB
    float2* ssv  = (float2*)(bins + NBINS);                         // 2 KB
    unsigned short* afb  = (unsigned short*)((char*)(ssv + C_OUT)); // 384 KB
    unsigned short* wt_b = afb + (size_t)NAFB;                      // 96 KB
    unsigned short* x_re = wt_b + (size_t)NWT;                      // 67.1 MB

    // single merged prep launch: bins zero + out_ap + afb + wt_b + x relayout
    k_prep<<<(PREP_ALL + 255) / 256, 256, 0, stream>>>(A, A_pers, conv_w, x,
                                                       bins, out_ap, afb, wt_b,
                                                       (unsigned*)x_re);

    dim3 grid(T_DIM / 8 * 64 * 4);   // 8192 flat, XCD-pinned decode in-kernel
    k_gemm<0><<<grid, 256, 0, stream>>>(x_re, afb, wt_b, y, bins, ssv);
    k_stats<<<1, 256, 0, stream>>>(bins, bn_w, bn_b, ssv, n);
    k_gemm<1><<<grid, 256, 0, stream>>>(x_re, afb, wt_b, y, bins, ssv);
}

// Round 22
// 256.474 us; speedup vs baseline: 1.0463x; 1.0078x over previous
//
#include <hip/hip_runtime.h>
#include <math.h>

#define C_IN   64
#define T_DIM  256
#define V_DIM  25
#define C_OUT  256
#define S_DIM  3
#define BN_EPS 1e-5f

#define SC       (S_DIM * C_IN)          // 192
#define TW       (T_DIM * V_DIM)         // 6400
#define AP_PER_N (S_DIM * V_DIM * V_DIM) // 1875
#define LDB      200                     // sXa row stride in bf16 (400 B)
#define LDY      204                     // yS row stride in f32 (816 B, breaks bank alias)
#define NR       32                      // atomic replica count

#define NBINS    (NR * 2 * C_OUT)        // 16384
#define NAP      (64 * AP_PER_N)         // 120000 (n=64)
#define NAFB     (64 * 6 * 64 * 8)       // 196608
#define NWT      (C_OUT * SC)            // 49152
#define PREP_TOT (NBINS + NAP + NAFB + NWT)
#define NXU      (64 * 128 * 128 * 16)   // x_re uints (2 bf16 each)
#define PREP_ALL (PREP_TOT + NXU)

typedef __attribute__((ext_vector_type(8))) short bf16x8;
typedef __attribute__((ext_vector_type(4))) float f32x4;

__device__ __forceinline__ unsigned short f2bf(float f) {
    unsigned u = __builtin_bit_cast(unsigned, f);
    unsigned r = u + 0x7fffu + ((u >> 16) & 1u);
    return (unsigned short)(r >> 16);
}

// Native casts -> compiler emits HW cvt (proven R11).
__device__ __forceinline__ unsigned pk_bf16(float a, float b) {
    unsigned short ul = __builtin_bit_cast(unsigned short, (__bf16)a);
    unsigned short uh = __builtin_bit_cast(unsigned short, (__bf16)b);
    return (unsigned)ul | ((unsigned)uh << 16);
}

// Non-temporal stores: y is write-once -> bypass L2.
__device__ __forceinline__ void nt_store_f4(f32x4 v, float* p) {
    __builtin_nontemporal_store(v, (f32x4*)p);
}

// ---------------------------------------------------------------------------
// Merged prep: zero bins | out_ap=tanh | afb pack | wt_b pack | x relayout.
// ---------------------------------------------------------------------------
__global__ void k_prep(const float* __restrict__ A, const float* __restrict__ A_pers,
                       const float* __restrict__ conv_w, const float* __restrict__ x,
                       float* __restrict__ bins, float* __restrict__ out_ap,
                       unsigned short* __restrict__ afb, unsigned short* __restrict__ wt_b,
                       unsigned* __restrict__ x_re) {
    int i = blockIdx.x * 256 + threadIdx.x;
    if (i < NBINS) {
        bins[i] = 0.f;
        return;
    }
    i -= NBINS;
    if (i < NAP) {
        out_ap[i] = tanhf(A_pers[i]);
        return;
    }
    i -= NAP;
    if (i < NAFB) {
        int j    = i;
        int k    = j & 7;
        int lane = (j >> 3) & 63;
        int nt   = (j >> 9) & 1;
        int sn   = j >> 10;
        int s    = sn % 3;
        int n    = sn / 3;
        int v    = ((lane >> 4) << 3) + k;
        int w    = nt * 16 + (lane & 15);
        float val = 0.f;
        if (v < V_DIM && w < V_DIM)
            val = A[(s * V_DIM + v) * V_DIM + w] +
                  tanhf(A_pers[((n * S_DIM + s) * V_DIM + v) * V_DIM + w]);
        afb[j] = f2bf(val);
        return;
    }
    i -= NAFB;
    if (i < NWT) {
        int o  = i / SC;
        int sc = i - o * SC;
        int s  = sc >> 6, c = sc & 63;
        wt_b[i] = f2bf(conv_w[(s * C_OUT + o) * C_IN + c]);
        return;
    }
    i -= NWT;
    if (i < NXU) {
        int tile = i >> 11;          // 2048 uints per tile
        int rem  = i & 2047;
        int row  = rem >> 4;         // 0..127 = 2c+t
        int vp   = rem & 15;         // uint col (v pair)
        int n = tile >> 7, tp = tile & 127;
        int c = row >> 1, t = row & 1;
        const float* src = x + (size_t)n * (C_IN * TW) + (size_t)c * TW + (2 * tp + t) * V_DIM;
        int v0 = vp * 2;
        unsigned lo = (v0 < V_DIM)     ? f2bf(src[v0])     : 0;
        unsigned hi = (v0 + 1 < V_DIM) ? f2bf(src[v0 + 1]) : 0;
        x_re[i] = lo | (hi << 16);
    }
}

// ---------------------------------------------------------------------------
// k_gemm<PASS>: flat grid 8192 with XCD-pinning swizzle: the 4 z-quarters of
// each (tp4, n) group share one XCD (d = xcd + 8*(4*grp + z)) -> their common
// x_re/afb reads hit that XCD's L2 instead of 4x HBM fetch.
// Per block: two half-iterations over a 2-tile sXa; acc[4][4] held.
// PASS 0: channel sum/sumsq -> shfl-reduce + replica atomics.
// PASS 1: BN+ReLU, f32 transpose into yS[64][204] -> 800B-run nt f32x4 writes.
// NOTE (R15/R16): z-loop-in-block spills registers; keep z in grid.
// NOTE (R20): 8 t-pairs/block regressed (more serial barrier rounds); tp4 is it.
// NOTE (R19): sXa pad rows tw=50..63 uninitialized — outputs discarded by guards.
// ---------------------------------------------------------------------------
template <int PASS>
__global__ __launch_bounds__(256, 3) void k_gemm(const unsigned short* __restrict__ x_re,
                                                 const unsigned short* __restrict__ afb,
                                                 const unsigned short* __restrict__ wt_b,
                                                 float* __restrict__ y,
                                                 float* __restrict__ bins,
                                                 const float2* __restrict__ ssv) {
    __shared__ __align__(16) char smem[64 * LDY * 4];    // 52224 B
    unsigned short* sXa = (unsigned short*)smem;         // [2][64*LDB] bf16 (51.2 KB)

    // XCD-pinned decode: group's 4 z-blocks all ≡ xcd (mod 8)
    const int d    = blockIdx.x;            // 0..8191
    const int xcd  = d & 7;
    const int q8   = d >> 3;
    const int z    = q8 & 3;                // o-quarter (64 channels)
    const int g    = (q8 >> 2) * 8 + xcd;   // group 0..2047 = n*32 + tp4
    const int tp4  = g & 31;
    const int nIdx = g >> 5;

    const int tid  = threadIdx.x;
    const int lane = tid & 63;
    const int wv   = tid >> 6;
    const int l15  = lane & 15;
    const int kg   = lane >> 4;
    const int obase = z * 64 + wv * 16;

    // ---- register-resident stage-2 weights (wave's 16-o strip): 6 x b128 ----
    bf16x8 aF[6];
    {
        const unsigned short* wrow = wt_b + (size_t)(z * 64 + wv * 16 + l15) * SC + kg * 8;
#pragma unroll
        for (int ks = 0; ks < 6; ++ks)
            aF[ks] = *(const bf16x8*)(wrow + ks * 32);
    }
    // ---- stage-1 B-frags (Af) ----
    bf16x8 bS[6];
    {
        const unsigned short* afbN = afb + (size_t)nIdx * (6 * 64 * 8);
#pragma unroll
        for (int sq = 0; sq < 6; ++sq)
            bS[sq] = *(const bf16x8*)(afbN + (sq * 64 + lane) * 8);
    }
    // ---- pass1: hoist BN scale/shift loads off the epilogue critical path ----
    float2 sh[4];
    if (PASS == 1) {
#pragma unroll
        for (int r = 0; r < 4; ++r)
            sh[r] = ssv[obase + kg * 4 + r];
    }

    f32x4 acc[4][4];
#pragma unroll
    for (int q = 0; q < 4; ++q)
#pragma unroll
        for (int nn = 0; nn < 4; ++nn) acc[q][nn] = (f32x4){0.f, 0.f, 0.f, 0.f};

#pragma unroll
    for (int h = 0; h < 2; ++h) {
        // ---- stage-1 A-frags for this half's 2 tiles ----
        bf16x8 aX[2][2];
        {
            const unsigned short* xt0 = x_re + (size_t)(nIdx * 128 + tp4 * 4 + h * 2) * 4096;
#pragma unroll
            for (int u = 0; u < 2; ++u)
#pragma unroll
                for (int m2 = 0; m2 < 2; ++m2)
                    aX[u][m2] = *(const bf16x8*)(xt0 + u * 4096 + ((wv * 2 + m2) * 16 + l15) * 32 + kg * 8);
        }

        // ---- stage 1: 24 MFMA/wave; packed bf16 b32 LDS writes ----
#pragma unroll
        for (int sq = 0; sq < 6; ++sq) {
            int s = sq >> 1, nt = sq & 1;
            int w = nt * 16 + l15;
#pragma unroll
            for (int u = 0; u < 2; ++u) {
#pragma unroll
                for (int m2 = 0; m2 < 2; ++m2) {
                    int mt = wv * 2 + m2;
                    f32x4 c4 = __builtin_amdgcn_mfma_f32_16x16x32_bf16(
                        aX[u][m2], bS[sq], (f32x4){0.f, 0.f, 0.f, 0.f}, 0, 0, 0);
                    if (w < V_DIM) {
                        unsigned u0 = pk_bf16(c4[0], c4[2]);   // t=0
                        unsigned u1 = pk_bf16(c4[1], c4[3]);   // t=1
                        unsigned col = s * 32 + mt * 4 + kg;
                        unsigned* dst = (unsigned*)(sXa + u * 12800);
                        dst[w * (LDB / 2) + col]           = u0;
                        dst[(V_DIM + w) * (LDB / 2) + col] = u1;
                    }
                }
            }
        }
        __syncthreads();   // sXa ready for stage 2

        // ---- stage 2: M=16/wave, K=192; acc[h*2+u]; MFMA cluster at prio 1 ----
#pragma unroll
        for (int ks = 0; ks < 6; ++ks) {
            bf16x8 bF[2][4];
#pragma unroll
            for (int u = 0; u < 2; ++u)
#pragma unroll
                for (int nn = 0; nn < 4; ++nn)
                    bF[u][nn] = *(const bf16x8*)(sXa + u * 12800 + (nn * 16 + l15) * LDB + ks * 32 + kg * 8);
            __builtin_amdgcn_s_setprio(1);
#pragma unroll
            for (int u = 0; u < 2; ++u)
#pragma unroll
                for (int nn = 0; nn < 4; ++nn)
                    acc[h * 2 + u][nn] = __builtin_amdgcn_mfma_f32_16x16x32_bf16(
                        aF[ks], bF[u][nn], acc[h * 2 + u][nn], 0, 0, 0);
            __builtin_amdgcn_s_setprio(0);
        }
        if (h == 0) __syncthreads();   // half-2 stage-1 may overwrite sXa
    }

    if (PASS == 0) {
        // ---- channel sums over all 4 tiles -> shfl-reduce, replica atomics ----
        const int rep = d & (NR - 1);
        float* b0 = bins + rep * 2 * C_OUT;
#pragma unroll
        for (int r = 0; r < 4; ++r) {
            float s1 = 0.f, s2 = 0.f;
#pragma unroll
            for (int q = 0; q < 4; ++q) {
                float v0 = acc[q][0][r], v1 = acc[q][1][r], v2 = acc[q][2][r];
                s1 += v0 + v1 + v2;
                s2 += v0 * v0 + v1 * v1 + v2 * v2;
                if (l15 < 2) {                   // tw = 48+l15 < 50
                    float v3 = acc[q][3][r];
                    s1 += v3;
                    s2 += v3 * v3;
                }
            }
#pragma unroll
            for (int off = 1; off < 16; off <<= 1) {
                s1 += __shfl_xor(s1, off, 64);
                s2 += __shfl_xor(s2, off, 64);
            }
            if (l15 == 0) {
                int o = obase + kg * 4 + r;
                atomicAdd(&b0[o], s1);
                atomicAdd(&b0[C_OUT + o], s2);
            }
        }
    } else {
        // ---- BN+ReLU; transpose via yS [64][204] f32; 800B-run nt f32x4 writes ----
        __syncthreads();                 // all sXa reads done before overwrite
        float* yS = (float*)smem;
#pragma unroll
        for (int r = 0; r < 4; ++r) {
            int ol = wv * 16 + kg * 4 + r;
            float sc = sh[r].x, sf = sh[r].y;
#pragma unroll
            for (int q = 0; q < 4; ++q) {
                float* sp = yS + ol * LDY + q * 50 + l15;
                sp[0]  = fmaxf(fmaf(acc[q][0][r], sc, sf), 0.f);
                sp[16] = fmaxf(fmaf(acc[q][1][r], sc, sf), 0.f);
                sp[32] = fmaxf(fmaf(acc[q][2][r], sc, sf), 0.f);
                if (l15 < 2)
                    sp[48] = fmaxf(fmaf(acc[q][3][r], sc, sf), 0.f);
            }
        }
        __syncthreads();

        // dump: 3200 f32x4 (16 B/lane); rows of 50 f32x4 = 800B contiguous per o;
        // incremental (o, j4) stepping (no per-iter division)
        float* ydst = y + ((size_t)nIdx * C_OUT + z * 64) * TW + (size_t)tp4 * 200;
        int o = tid / 50, j4 = tid - (tid / 50) * 50;
#pragma unroll
        for (int k = 0; k < 13; ++k) {
            if (k < 12 || tid < 128) {          // 3200 = 12*256 + 128
                f32x4 v = *(const f32x4*)(yS + o * LDY + 4 * j4);
                nt_store_f4(v, ydst + (size_t)o * TW + 4 * j4);
            }
            o += 5; j4 += 6;
            if (j4 >= 50) { j4 -= 50; ++o; }
        }
    }
}

// ---------------------------------------------------------------------------
__global__ void k_stats(const float* __restrict__ bins, const float* __restrict__ bn_w,
                        const float* __restrict__ bn_b, float2* __restrict__ ssv, int n) {
    int o = threadIdx.x;
    float s1 = 0.f, s2 = 0.f;
    for (int rp = 0; rp < NR; ++rp) {
        s1 += bins[rp * 2 * C_OUT + o];
        s2 += bins[rp * 2 * C_OUT + C_OUT + o];
    }
    float cnt   = (float)n * (float)TW;
    float mean  = s1 / cnt;
    float var   = s2 / cnt - mean * mean;
    float scale = bn_w[o] * rsqrtf(var + BN_EPS);
    ssv[o] = make_float2(scale, bn_b[o] - mean * scale);
}

// ---------------------------------------------------------------------------
extern "C" void kernel_launch(void* const* d_in, const int* in_sizes, int n_in,
                              void* d_out, int out_size, void* d_ws, size_t ws_size,
                              hipStream_t stream) {
    const float* x      = (const float*)d_in[0];
    const float* A      = (const float*)d_in[1];
    const float* A_pers = (const float*)d_in[2];
    const float* conv_w = (const float*)d_in[3];
    // d_in[4] = conv_b: cancels under training-mode BatchNorm -> unused
    const float* bn_w   = (const float*)d_in[5];
    const float* bn_b   = (const float*)d_in[6];

    const int n = in_sizes[0] / (C_IN * TW);   // 64

    float* out_ap = (float*)d_out;
    float* y      = (float*)d_out + (size_t)n * AP_PER_N;

    // ws layout (~67.7 MB total)
    float*  bins = (float*)d_ws;                                    // 64 KB
    float2* ssv  = (float2*)(bins + NBINS);                         // 2 KB
    unsigned short* afb  = (unsigned short*)((char*)(ssv + C_OUT)); // 384 KB
    unsigned short* wt_b = afb + (size_t)NAFB;                      // 96 KB
    unsigned short* x_re = wt_b + (size_t)NWT;                      // 67.1 MB

    // single merged prep launch: bins zero + out_ap + afb + wt_b + x relayout
    k_prep<<<(PREP_ALL + 255) / 256, 256, 0, stream>>>(A, A_pers, conv_w, x,
                                                       bins, out_ap, afb, wt_b,
                                                       (unsigned*)x_re);

    dim3 grid(T_DIM / 8 * 64 * 4);   // 8192 flat, XCD-pinned decode in-kernel
    k_gemm<0><<<grid, 256, 0, stream>>>(x_re, afb, wt_b, y, bins, ssv);
    k_stats<<<1, 256, 0, stream>>>(bins, bn_w, bn_b, ssv, n);
    k_gemm<1><<<grid, 256, 0, stream>>>(x_re, afb, wt_b, y, bins, ssv);
}